// Round 2
// baseline (7050.935 us; speedup 1.0000x reference)
//
#include <hip/hip_runtime.h>

// ============================================================================
// 2-layer tanh RNN (B=128,S=512,IN=128,H=512) + linear head (C=1000) + logsoftmax
//
// Round-2 redesign: batch-partitioned recurrence, ZERO cross-WG sync.
//   - 8 WGs x 256 thr; WG owns 16 batches and the FULL H=512.
//   - W_hh pre-packed to bf16 MFMA A-frag layout (prepack_kernel).
//   - k-tiles 0..9 of W live in VGPRs (320/thread); k-tiles 10..15 streamed
//     from L2 each step (192 KB/CU/step), ping-pong double-buffered.
//   - h state in LDS [2][16][520] bf16, one __syncthreads per step.
//
// ws layout (128 MB total, all aliased carefully):
//   bufA = ws + 0    (64 MB)   xp0 / hs0 (in place), later: Wpk1 @ head, hlast @ +1MB
//   bufB = ws + 64MB (64 MB)   Wpk0 @ head (pre-proj1), later xp1
// Launch order: prepack0->bufB | proj0->bufA | rec0(Wpk0=bufB,xp=hs=bufA)
//             | proj1(bufA->bufB) | prepack1->bufA | rec1(Wpk1=bufA,xp=bufB)
//             | head(hlast=bufA+1MB)
// ============================================================================

using short8  = __attribute__((ext_vector_type(8))) short;
using floatx4 = __attribute__((ext_vector_type(4))) float;

#define DEV static __device__ __forceinline__

DEV unsigned short f2bf(float f) {
    union { float f; unsigned u; } v; v.f = f;
    unsigned r = (v.u + 0x7fffu + ((v.u >> 16) & 1u)) >> 16;
    return (unsigned short)r;
}
DEV float bf2f(unsigned short h) {
    union { unsigned u; float f; } v; v.u = ((unsigned)h) << 16;
    return v.f;
}
DEV float tanh_fast(float x) {
    float ax = fabsf(x);
    ax = fminf(ax, 12.0f);
    float e = __expf(-2.0f * ax);
    float r = (1.0f - e) / (1.0f + e);
    return copysignf(r, x);
}

// ---------------------------------------------------------------------------
// prepack: W_hh fp32 [512][512] -> bf16 A-frag order.
// frag = jtg*16 + kt (jtg 0..31, kt 0..15); within frag: lane*8 elems,
// elem e: j = jtg*16 + (lane&15), k = kt*32 + (lane>>4)*8 + e.
// grid 128 x 256.
// ---------------------------------------------------------------------------
__global__ void prepack_kernel(const float* __restrict__ W,
                               unsigned short* __restrict__ Wpk)
{
    const int gid  = blockIdx.x * 256 + threadIdx.x;   // 0..32767
    const int lane = gid & 63;
    const int frag = gid >> 6;                         // 0..511
    const int kt   = frag & 15;
    const int jtg  = frag >> 4;
    const int j    = jtg * 16 + (lane & 15);
    const int k    = kt * 32 + (lane >> 4) * 8;
    const float* src = W + (size_t)j * 512 + k;
    float4 a = *(const float4*)(src);
    float4 b = *(const float4*)(src + 4);
    short8 p;
    p[0]=(short)f2bf(a.x); p[1]=(short)f2bf(a.y);
    p[2]=(short)f2bf(a.z); p[3]=(short)f2bf(a.w);
    p[4]=(short)f2bf(b.x); p[5]=(short)f2bf(b.y);
    p[6]=(short)f2bf(b.z); p[7]=(short)f2bf(b.w);
    *(short8*)(Wpk + (size_t)gid * 8) = p;
}

// ---------------------------------------------------------------------------
// proj: out[m=t*128+b][n] = bf16( A[m][:]·W[n][:] + b1[n]+b2[n] )   (unchanged)
// ---------------------------------------------------------------------------
template <int K, int MODE>
__global__ __launch_bounds__(256, 2) void proj_kernel(
    const void* __restrict__ Aptr, const float* __restrict__ W,
    const float* __restrict__ b1, const float* __restrict__ b2,
    unsigned short* __restrict__ out)
{
    constexpr int LDA = 40;
    __shared__ unsigned short As[128 * LDA];
    __shared__ unsigned short Ws[64 * LDA];

    const int tid  = threadIdx.x;
    const int lane = tid & 63, wave = tid >> 6;
    const int lm   = lane & 15, lq = lane >> 4;
    const int nbase = blockIdx.x * 64;
    const int mtile = blockIdx.y;
    const int mbase = mtile * 128;

    floatx4 acc[2][4] = {};

    const int ar = tid >> 1, ak = (tid & 1) * 16;
    const int wr = tid >> 2, wk = (tid & 3) * 8;

    for (int k0 = 0; k0 < K; k0 += 32) {
        if (MODE == 0) {
            const float* x   = (const float*)Aptr;
            const float* src = x + ((size_t)ar * 512 + mtile) * 128 + (k0 + ak);
            float4 f0 = *(const float4*)(src + 0);
            float4 f1 = *(const float4*)(src + 4);
            float4 f2 = *(const float4*)(src + 8);
            float4 f3 = *(const float4*)(src + 12);
            unsigned short* d = As + ar * LDA + ak;
            d[0]=f2bf(f0.x); d[1]=f2bf(f0.y); d[2]=f2bf(f0.z); d[3]=f2bf(f0.w);
            d[4]=f2bf(f1.x); d[5]=f2bf(f1.y); d[6]=f2bf(f1.z); d[7]=f2bf(f1.w);
            d[8]=f2bf(f2.x); d[9]=f2bf(f2.y); d[10]=f2bf(f2.z); d[11]=f2bf(f2.w);
            d[12]=f2bf(f3.x); d[13]=f2bf(f3.y); d[14]=f2bf(f3.z); d[15]=f2bf(f3.w);
        } else {
            const unsigned short* h =
                (const unsigned short*)Aptr + (size_t)(mbase + ar) * K + k0 + ak;
            short8 v0 = *(const short8*)(h);
            short8 v1 = *(const short8*)(h + 8);
            *(short8*)(As + ar * LDA + ak)     = v0;
            *(short8*)(As + ar * LDA + ak + 8) = v1;
        }
        {
            const float* src = W + (size_t)(nbase + wr) * K + k0 + wk;
            float4 f0 = *(const float4*)(src);
            float4 f1 = *(const float4*)(src + 4);
            unsigned short* d = Ws + wr * LDA + wk;
            d[0]=f2bf(f0.x); d[1]=f2bf(f0.y); d[2]=f2bf(f0.z); d[3]=f2bf(f0.w);
            d[4]=f2bf(f1.x); d[5]=f2bf(f1.y); d[6]=f2bf(f1.z); d[7]=f2bf(f1.w);
        }
        __syncthreads();

        short8 af0 = *(const short8*)(As + (wave * 32 +  0 + lm) * LDA + lq * 8);
        short8 af1 = *(const short8*)(As + (wave * 32 + 16 + lm) * LDA + lq * 8);
        #pragma unroll
        for (int nt = 0; nt < 4; ++nt) {
            short8 bf = *(const short8*)(Ws + (nt * 16 + lm) * LDA + lq * 8);
            acc[0][nt] = __builtin_amdgcn_mfma_f32_16x16x32_bf16(af0, bf, acc[0][nt], 0, 0, 0);
            acc[1][nt] = __builtin_amdgcn_mfma_f32_16x16x32_bf16(af1, bf, acc[1][nt], 0, 0, 0);
        }
        __syncthreads();
    }

    #pragma unroll
    for (int nt = 0; nt < 4; ++nt) {
        const int n = nbase + nt * 16 + lm;
        const float bias = b1[n] + b2[n];
        #pragma unroll
        for (int mt = 0; mt < 2; ++mt) {
            const int mrow = mbase + wave * 32 + mt * 16 + lq * 4;
            #pragma unroll
            for (int r = 0; r < 4; ++r)
                out[(size_t)(mrow + r) * 512 + n] = f2bf(acc[mt][nt][r] + bias);
        }
    }
}

// ---------------------------------------------------------------------------
// rec2: batch-partitioned recurrence, no cross-WG sync.
// grid 8 x 256 thr; WG bg owns batches [bg*16, bg*16+16), full H=512.
// wave (4 of them) owns j-tiles jtg = wave*8 .. wave*8+7.
// W A-frags: kt 0..9 resident in VGPRs; kt 10..15 streamed (ping-pong).
// h: LDS [2][16][520] bf16; read buf (t&1), write buf (t&1)^1; 1 barrier/step.
// mode 0: also store h_t to hs_out (aliases xp in-place, same thread+addr).
// mode 1: store only t=511 as fp32 to h_last.
// ---------------------------------------------------------------------------
#define LDH 520

__global__ __launch_bounds__(256, 1) void rec2_kernel(
    const unsigned short* __restrict__ Wpk,  // [512 frag][64 lane][8] bf16
    const unsigned short* xp,                // [S][B][H] bf16 (aliases hs_out)
    unsigned short* hs_out,                  // [S][B][H] bf16
    float* __restrict__ h_last,              // [B][H] fp32
    int mode)
{
    __shared__ unsigned short h2[2][16][LDH];   // 33,280 B

    const int tid  = threadIdx.x;
    const int lane = tid & 63;
    const int wave = tid >> 6;
    const int lm   = lane & 15, lq = lane >> 4;
    const int bg   = blockIdx.x;
    const int bb   = bg * 16 + lm;              // this lane's batch column

    // ---- resident W frags: kt 0..9 for this wave's 8 j-tiles (320 VGPRs) ----
    short8 wreg[8][10];
    #pragma unroll
    for (int j = 0; j < 8; ++j) {
        const int jtg = wave * 8 + j;
        #pragma unroll
        for (int kt = 0; kt < 10; ++kt)
            wreg[j][kt] = *(const short8*)(Wpk + ((size_t)(jtg * 16 + kt) * 64 + lane) * 8);
    }

    // ---- zero h buffers ----
    for (int i = tid; i < 2 * 16 * LDH; i += 256)
        ((unsigned short*)h2)[i] = 0;
    __syncthreads();

    for (int t = 0; t < 512; ++t) {
        const int p = t & 1;
        const unsigned short* hrl = &h2[p][lm][0];        // read h_{t-1}
        unsigned short*       hwl = &h2[p ^ 1][lm][0];    // write h_t

        // ---- stream issue: kt 10, 11 (ping-pong buffers) ----
        short8 sA[8], sB[8];
        #pragma unroll
        for (int j = 0; j < 8; ++j)
            sA[j] = *(const short8*)(Wpk + ((size_t)((wave * 8 + j) * 16 + 10) * 64 + lane) * 8);
        #pragma unroll
        for (int j = 0; j < 8; ++j)
            sB[j] = *(const short8*)(Wpk + ((size_t)((wave * 8 + j) * 16 + 11) * 64 + lane) * 8);

        // ---- xp operands for epilogue (issue early) ----
        const size_t xrow = ((size_t)t * 128 + bb) * 512;
        ushort4 xv[8];
        #pragma unroll
        for (int j = 0; j < 8; ++j)
            xv[j] = *(const ushort4*)(xp + xrow + (wave * 8 + j) * 16 + lq * 4);

        floatx4 acc[8] = {};

        // ---- resident compute: kt 0..9 ----
        #pragma unroll
        for (int kt = 0; kt < 10; ++kt) {
            short8 bfr = *(const short8*)(hrl + kt * 32 + lq * 8);
            #pragma unroll
            for (int j = 0; j < 8; ++j)
                acc[j] = __builtin_amdgcn_mfma_f32_16x16x32_bf16(wreg[j][kt], bfr, acc[j], 0, 0, 0);
        }

        // ---- streamed compute: kt 10..15, ping-pong reissue ----
        {   // kt 10 (sA), reissue kt 12 -> sA
            short8 bfr = *(const short8*)(hrl + 10 * 32 + lq * 8);
            #pragma unroll
            for (int j = 0; j < 8; ++j)
                acc[j] = __builtin_amdgcn_mfma_f32_16x16x32_bf16(sA[j], bfr, acc[j], 0, 0, 0);
            #pragma unroll
            for (int j = 0; j < 8; ++j)
                sA[j] = *(const short8*)(Wpk + ((size_t)((wave * 8 + j) * 16 + 12) * 64 + lane) * 8);
        }
        {   // kt 11 (sB), reissue kt 13 -> sB
            short8 bfr = *(const short8*)(hrl + 11 * 32 + lq * 8);
            #pragma unroll
            for (int j = 0; j < 8; ++j)
                acc[j] = __builtin_amdgcn_mfma_f32_16x16x32_bf16(sB[j], bfr, acc[j], 0, 0, 0);
            #pragma unroll
            for (int j = 0; j < 8; ++j)
                sB[j] = *(const short8*)(Wpk + ((size_t)((wave * 8 + j) * 16 + 13) * 64 + lane) * 8);
        }
        {   // kt 12 (sA), reissue kt 14 -> sA
            short8 bfr = *(const short8*)(hrl + 12 * 32 + lq * 8);
            #pragma unroll
            for (int j = 0; j < 8; ++j)
                acc[j] = __builtin_amdgcn_mfma_f32_16x16x32_bf16(sA[j], bfr, acc[j], 0, 0, 0);
            #pragma unroll
            for (int j = 0; j < 8; ++j)
                sA[j] = *(const short8*)(Wpk + ((size_t)((wave * 8 + j) * 16 + 14) * 64 + lane) * 8);
        }
        {   // kt 13 (sB), reissue kt 15 -> sB
            short8 bfr = *(const short8*)(hrl + 13 * 32 + lq * 8);
            #pragma unroll
            for (int j = 0; j < 8; ++j)
                acc[j] = __builtin_amdgcn_mfma_f32_16x16x32_bf16(sB[j], bfr, acc[j], 0, 0, 0);
            #pragma unroll
            for (int j = 0; j < 8; ++j)
                sB[j] = *(const short8*)(Wpk + ((size_t)((wave * 8 + j) * 16 + 15) * 64 + lane) * 8);
        }
        {   // kt 14 (sA)
            short8 bfr = *(const short8*)(hrl + 14 * 32 + lq * 8);
            #pragma unroll
            for (int j = 0; j < 8; ++j)
                acc[j] = __builtin_amdgcn_mfma_f32_16x16x32_bf16(sA[j], bfr, acc[j], 0, 0, 0);
        }
        {   // kt 15 (sB)
            short8 bfr = *(const short8*)(hrl + 15 * 32 + lq * 8);
            #pragma unroll
            for (int j = 0; j < 8; ++j)
                acc[j] = __builtin_amdgcn_mfma_f32_16x16x32_bf16(sB[j], bfr, acc[j], 0, 0, 0);
        }

        // ---- epilogue: j = (wave*8+j)*16 + lq*4 + r, batch col = bb ----
        #pragma unroll
        for (int j = 0; j < 8; ++j) {
            const int jb = (wave * 8 + j) * 16 + lq * 4;
            float q0 = tanh_fast(acc[j][0] + bf2f(xv[j].x));
            float q1 = tanh_fast(acc[j][1] + bf2f(xv[j].y));
            float q2 = tanh_fast(acc[j][2] + bf2f(xv[j].z));
            float q3 = tanh_fast(acc[j][3] + bf2f(xv[j].w));
            ushort4 pk;
            pk.x = f2bf(q0); pk.y = f2bf(q1); pk.z = f2bf(q2); pk.w = f2bf(q3);
            *(ushort4*)(hwl + jb) = pk;
            if (mode == 0) {
                *(ushort4*)(hs_out + xrow + jb) = pk;
            } else if (t == 511) {
                float4 o; o.x = q0; o.y = q1; o.z = q2; o.w = q3;
                *(float4*)(h_last + (size_t)bb * 512 + jb) = o;
            }
        }
        __syncthreads();
    }
}

// ---------------------------------------------------------------------------
// head: logits[b][c] = h_last[b][:]·W_out[c][:] + b_out[c]; log_softmax rows.
// ---------------------------------------------------------------------------
__global__ __launch_bounds__(256, 2) void head_kernel(
    const float* __restrict__ hl, const float* __restrict__ Wout,
    const float* __restrict__ bout, float* __restrict__ out)
{
    __shared__ float hrow[512];
    __shared__ float lg[1000];
    __shared__ float red[8];
    const int b = blockIdx.x, tid = threadIdx.x;

    hrow[tid]       = hl[(size_t)b * 512 + tid];
    hrow[tid + 256] = hl[(size_t)b * 512 + 256 + tid];
    __syncthreads();

    float lmax = -1e30f;
    for (int c = tid; c < 1000; c += 256) {
        const float4* w4 = (const float4*)(Wout + (size_t)c * 512);
        float a0 = 0.f, a1 = 0.f, a2 = 0.f, a3 = 0.f;
        #pragma unroll 4
        for (int k = 0; k < 128; ++k) {
            float4 w = w4[k];
            a0 += hrow[4 * k + 0] * w.x;
            a1 += hrow[4 * k + 1] * w.y;
            a2 += hrow[4 * k + 2] * w.z;
            a3 += hrow[4 * k + 3] * w.w;
        }
        float acc = bout[c] + (a0 + a1) + (a2 + a3);
        lg[c] = acc;
        lmax = fmaxf(lmax, acc);
    }
    #pragma unroll
    for (int off = 32; off; off >>= 1) lmax = fmaxf(lmax, __shfl_down(lmax, off, 64));
    if ((tid & 63) == 0) red[tid >> 6] = lmax;
    __syncthreads();
    if (tid == 0) red[4] = fmaxf(fmaxf(red[0], red[1]), fmaxf(red[2], red[3]));
    __syncthreads();
    const float M = red[4];

    float lsum = 0.f;
    for (int c = tid; c < 1000; c += 256) lsum += __expf(lg[c] - M);
    #pragma unroll
    for (int off = 32; off; off >>= 1) lsum += __shfl_down(lsum, off, 64);
    __syncthreads();
    if ((tid & 63) == 0) red[tid >> 6] = lsum;
    __syncthreads();
    if (tid == 0) red[5] = M + __logf(red[0] + red[1] + red[2] + red[3]);
    __syncthreads();
    const float lse = red[5];

    for (int c = tid; c < 1000; c += 256)
        out[(size_t)b * 1000 + c] = lg[c] - lse;
}

// ---------------------------------------------------------------------------
extern "C" void kernel_launch(void* const* d_in, const int* in_sizes, int n_in,
                              void* d_out, int out_size, void* d_ws, size_t ws_size,
                              hipStream_t stream)
{
    const float* x    = (const float*)d_in[0];
    const float* Wih0 = (const float*)d_in[1];
    const float* Whh0 = (const float*)d_in[2];
    const float* bih0 = (const float*)d_in[3];
    const float* bhh0 = (const float*)d_in[4];
    const float* Wih1 = (const float*)d_in[5];
    const float* Whh1 = (const float*)d_in[6];
    const float* bih1 = (const float*)d_in[7];
    const float* bhh1 = (const float*)d_in[8];
    const float* Wout = (const float*)d_in[9];
    const float* bout = (const float*)d_in[10];
    float* out = (float*)d_out;

    char* ws = (char*)d_ws;
    unsigned short* bufA = (unsigned short*)ws;                             // 64 MB
    unsigned short* bufB = (unsigned short*)(ws + (size_t)64 * 1024 * 1024);
    // Wpk0 lives at the head of bufB (dead until proj1 overwrites it).
    unsigned short* Wpk0 = bufB;                                            // 512 KB
    // Wpk1 + hlast live inside bufA (dead after proj1 reads it).
    unsigned short* Wpk1 = bufA;                                            // 512 KB
    float*         hlast = (float*)(ws + (size_t)1 * 1024 * 1024);          // 256 KB @ bufA+1MB

    const dim3 pgrid(8, 512);

    prepack_kernel<<<128, 256, 0, stream>>>(Whh0, Wpk0);
    proj_kernel<128, 0><<<pgrid, 256, 0, stream>>>((const void*)x, Wih0, bih0, bhh0, bufA);
    rec2_kernel<<<8, 256, 0, stream>>>(Wpk0, bufA, bufA, hlast, 0);

    proj_kernel<512, 1><<<pgrid, 256, 0, stream>>>((const void*)bufA, Wih1, bih1, bhh1, bufB);
    prepack_kernel<<<128, 256, 0, stream>>>(Whh1, Wpk1);
    rec2_kernel<<<8, 256, 0, stream>>>(Wpk1, bufB, bufB, hlast, 1);

    head_kernel<<<128, 256, 0, stream>>>(hlast, Wout, bout, out);
}

// Round 3
// 3747.326 us; speedup vs baseline: 1.8816x; 1.8816x over previous
//
#include <hip/hip_runtime.h>

// ============================================================================
// 2-layer tanh RNN (B=128,S=512,IN=128,H=512) + linear head (C=1000) + logsoftmax
//
// Round-3: batch-partitioned recurrence (8 WGs, zero cross-WG sync), with
//   - 512 thr/WG (8 waves, 2/SIMD for TLP), 256 reg/thread cap, NO overcommit
//   - W_hh split: kt 0..9 in VGPRs (160/thread), kt 10..12 in LDS (96 KB,
//     loaded once), kt 13..15 streamed from L2 each step (96 KB, prefetched
//     at step-top, consumed last -> latency hidden)
//   - h state: LDS [2][16][512] bf16 double buffer with 16B-granule XOR
//     swizzle (granule ^= b&7) -> minimum-phase ds_read_b128 / ds_write_b64
//   - 1 __syncthreads per step
//
// ws layout (identical to round 2):
//   bufA = ws + 0    (64 MB)   xp0/hs0 in place; later Wpk1 @ head, hlast @ +1MB
//   bufB = ws + 64MB (64 MB)   Wpk0 @ head; later xp1
// ============================================================================

using short8  = __attribute__((ext_vector_type(8))) short;
using floatx4 = __attribute__((ext_vector_type(4))) float;

#define DEV static __device__ __forceinline__

DEV unsigned short f2bf(float f) {
    union { float f; unsigned u; } v; v.f = f;
    unsigned r = (v.u + 0x7fffu + ((v.u >> 16) & 1u)) >> 16;
    return (unsigned short)r;
}
DEV float bf2f(unsigned short h) {
    union { unsigned u; float f; } v; v.u = ((unsigned)h) << 16;
    return v.f;
}
DEV float tanh_fast(float x) {
    // tanh(x) = 1 - 2/(e^{2x}+1); inf-safe at both ends
    float e = __expf(2.0f * x);
    return 1.0f - 2.0f * __builtin_amdgcn_rcpf(e + 1.0f);
}

// ---------------------------------------------------------------------------
// prepack: W_hh fp32 [512][512] -> bf16 A-frag order.
// frag = jtg*16 + kt; within frag: lane holds j = jtg*16+(lane&15),
// k = kt*32 + (lane>>4)*8 + e  (e=0..7).
// ---------------------------------------------------------------------------
__global__ void prepack_kernel(const float* __restrict__ W,
                               unsigned short* __restrict__ Wpk)
{
    const int gid  = blockIdx.x * 256 + threadIdx.x;   // 0..32767
    const int lane = gid & 63;
    const int frag = gid >> 6;                         // 0..511
    const int kt   = frag & 15;
    const int jtg  = frag >> 4;
    const int j    = jtg * 16 + (lane & 15);
    const int k    = kt * 32 + (lane >> 4) * 8;
    const float* src = W + (size_t)j * 512 + k;
    float4 a = *(const float4*)(src);
    float4 b = *(const float4*)(src + 4);
    short8 p;
    p[0]=(short)f2bf(a.x); p[1]=(short)f2bf(a.y);
    p[2]=(short)f2bf(a.z); p[3]=(short)f2bf(a.w);
    p[4]=(short)f2bf(b.x); p[5]=(short)f2bf(b.y);
    p[6]=(short)f2bf(b.z); p[7]=(short)f2bf(b.w);
    *(short8*)(Wpk + (size_t)gid * 8) = p;
}

// ---------------------------------------------------------------------------
// proj: out[m=t*128+b][n] = bf16( A[m][:]·W[n][:] + b1[n]+b2[n] )  (unchanged)
// ---------------------------------------------------------------------------
template <int K, int MODE>
__global__ __launch_bounds__(256, 2) void proj_kernel(
    const void* __restrict__ Aptr, const float* __restrict__ W,
    const float* __restrict__ b1, const float* __restrict__ b2,
    unsigned short* __restrict__ out)
{
    constexpr int LDA = 40;
    __shared__ unsigned short As[128 * LDA];
    __shared__ unsigned short Ws[64 * LDA];

    const int tid  = threadIdx.x;
    const int lane = tid & 63, wave = tid >> 6;
    const int lm   = lane & 15, lq = lane >> 4;
    const int nbase = blockIdx.x * 64;
    const int mtile = blockIdx.y;
    const int mbase = mtile * 128;

    floatx4 acc[2][4] = {};

    const int ar = tid >> 1, ak = (tid & 1) * 16;
    const int wr = tid >> 2, wk = (tid & 3) * 8;

    for (int k0 = 0; k0 < K; k0 += 32) {
        if (MODE == 0) {
            const float* x   = (const float*)Aptr;
            const float* src = x + ((size_t)ar * 512 + mtile) * 128 + (k0 + ak);
            float4 f0 = *(const float4*)(src + 0);
            float4 f1 = *(const float4*)(src + 4);
            float4 f2 = *(const float4*)(src + 8);
            float4 f3 = *(const float4*)(src + 12);
            unsigned short* d = As + ar * LDA + ak;
            d[0]=f2bf(f0.x); d[1]=f2bf(f0.y); d[2]=f2bf(f0.z); d[3]=f2bf(f0.w);
            d[4]=f2bf(f1.x); d[5]=f2bf(f1.y); d[6]=f2bf(f1.z); d[7]=f2bf(f1.w);
            d[8]=f2bf(f2.x); d[9]=f2bf(f2.y); d[10]=f2bf(f2.z); d[11]=f2bf(f2.w);
            d[12]=f2bf(f3.x); d[13]=f2bf(f3.y); d[14]=f2bf(f3.z); d[15]=f2bf(f3.w);
        } else {
            const unsigned short* h =
                (const unsigned short*)Aptr + (size_t)(mbase + ar) * K + k0 + ak;
            short8 v0 = *(const short8*)(h);
            short8 v1 = *(const short8*)(h + 8);
            *(short8*)(As + ar * LDA + ak)     = v0;
            *(short8*)(As + ar * LDA + ak + 8) = v1;
        }
        {
            const float* src = W + (size_t)(nbase + wr) * K + k0 + wk;
            float4 f0 = *(const float4*)(src);
            float4 f1 = *(const float4*)(src + 4);
            unsigned short* d = Ws + wr * LDA + wk;
            d[0]=f2bf(f0.x); d[1]=f2bf(f0.y); d[2]=f2bf(f0.z); d[3]=f2bf(f0.w);
            d[4]=f2bf(f1.x); d[5]=f2bf(f1.y); d[6]=f2bf(f1.z); d[7]=f2bf(f1.w);
        }
        __syncthreads();

        short8 af0 = *(const short8*)(As + (wave * 32 +  0 + lm) * LDA + lq * 8);
        short8 af1 = *(const short8*)(As + (wave * 32 + 16 + lm) * LDA + lq * 8);
        #pragma unroll
        for (int nt = 0; nt < 4; ++nt) {
            short8 bf = *(const short8*)(Ws + (nt * 16 + lm) * LDA + lq * 8);
            acc[0][nt] = __builtin_amdgcn_mfma_f32_16x16x32_bf16(af0, bf, acc[0][nt], 0, 0, 0);
            acc[1][nt] = __builtin_amdgcn_mfma_f32_16x16x32_bf16(af1, bf, acc[1][nt], 0, 0, 0);
        }
        __syncthreads();
    }

    #pragma unroll
    for (int nt = 0; nt < 4; ++nt) {
        const int n = nbase + nt * 16 + lm;
        const float bias = b1[n] + b2[n];
        #pragma unroll
        for (int mt = 0; mt < 2; ++mt) {
            const int mrow = mbase + wave * 32 + mt * 16 + lq * 4;
            #pragma unroll
            for (int r = 0; r < 4; ++r)
                out[(size_t)(mrow + r) * 512 + n] = f2bf(acc[mt][nt][r] + bias);
        }
    }
}

// ---------------------------------------------------------------------------
// rec3: 8 WGs x 512 thr (8 waves, 2/SIMD). WG bg owns batches [bg*16,+16),
// full H=512. Wave owns 4 j-tiles (jtg = wave*4 .. +3, 64 j rows).
//  - wreg: kt 0..9 resident (40 short8 = 160 VGPR/thread)
//  - wlds: kt 10..12 in LDS [3][32 jtg][64 lane][8] (96 KB, loaded once)
//  - stream: kt 13..15 from L2, prefetched at step top (48 VGPR)
//  - h2: LDS [2][16 b][512] bf16, XOR-swizzled 16B granules (g ^= b&7)
// mode 0: also store h_t to hs_out (in-place over xp: same thread+addr).
// mode 1: store only t=511 as fp32 to h_last.
// ---------------------------------------------------------------------------
__global__ __launch_bounds__(512, 2) void rec3_kernel(
    const unsigned short* __restrict__ Wpk,  // [512 frag][64 lane][8] bf16
    const unsigned short* xp,                // [S][B][H] bf16 (aliases hs_out)
    unsigned short* hs_out,                  // [S][B][H] bf16
    float* __restrict__ h_last,              // [B][H] fp32
    int mode)
{
    __shared__ unsigned short h2[2][16 * 512];      // 32 KB
    __shared__ unsigned short wlds[3 * 32 * 64 * 8]; // 96 KB

    const int tid  = threadIdx.x;
    const int lane = tid & 63;
    const int wave = tid >> 6;                 // 0..7
    const int lm   = lane & 15, lq = lane >> 4;
    const int bg   = blockIdx.x;
    const int bb   = bg * 16 + lm;             // this lane's batch column
    const int lmx  = lm & 7;                   // swizzle key

    // ---- resident W frags: kt 0..9 for this wave's 4 j-tiles ----
    short8 wreg[4][10];
    #pragma unroll
    for (int j = 0; j < 4; ++j) {
        const int jtg = wave * 4 + j;
        #pragma unroll
        for (int kt = 0; kt < 10; ++kt)
            wreg[j][kt] = *(const short8*)(Wpk + ((size_t)(jtg * 16 + kt) * 64 + lane) * 8);
    }

    // ---- load W kt 10..12 into LDS (layout [ktl][jtg][lane][8]) ----
    for (int i = tid; i < 3 * 32 * 64; i += 512) {
        const int l_  = i & 63;
        const int jg_ = (i >> 6) & 31;
        const int kl_ = i >> 11;              // 0..2
        *(short8*)(wlds + (size_t)i * 8) =
            *(const short8*)(Wpk + ((size_t)(jg_ * 16 + 10 + kl_) * 64 + l_) * 8);
    }

    // ---- zero h buffers ----
    for (int i = tid; i < 2 * 16 * 512; i += 512)
        ((unsigned short*)h2)[i] = 0;
    __syncthreads();

    for (int t = 0; t < 512; ++t) {
        const int p = t & 1;
        const unsigned short* hp = &h2[p][0];       // read h_{t-1}
        unsigned short*       hw = &h2[p ^ 1][0];   // write h_t

        // ---- prefetch stream W: kt 13..15 (used at end of step) ----
        short8 sA[4], sB[4], sC[4];
        #pragma unroll
        for (int j = 0; j < 4; ++j)
            sA[j] = *(const short8*)(Wpk + ((size_t)((wave * 4 + j) * 16 + 13) * 64 + lane) * 8);
        #pragma unroll
        for (int j = 0; j < 4; ++j)
            sB[j] = *(const short8*)(Wpk + ((size_t)((wave * 4 + j) * 16 + 14) * 64 + lane) * 8);
        #pragma unroll
        for (int j = 0; j < 4; ++j)
            sC[j] = *(const short8*)(Wpk + ((size_t)((wave * 4 + j) * 16 + 15) * 64 + lane) * 8);

        // ---- xp operands for epilogue (issue early) ----
        const size_t xrow = ((size_t)t * 128 + bb) * 512;
        ushort4 xv[4];
        #pragma unroll
        for (int j = 0; j < 4; ++j)
            xv[j] = *(const ushort4*)(xp + xrow + (wave * 4 + j) * 16 + lq * 4);

        floatx4 acc[4] = {};

        // ---- kt 0..9 from registers; h B-frag from swizzled LDS ----
        #pragma unroll
        for (int kt = 0; kt < 10; ++kt) {
            short8 bfr = *(const short8*)(hp + lm * 512 + ((((kt << 2) + lq) ^ lmx) << 3));
            #pragma unroll
            for (int j = 0; j < 4; ++j)
                acc[j] = __builtin_amdgcn_mfma_f32_16x16x32_bf16(wreg[j][kt], bfr, acc[j], 0, 0, 0);
        }
        // ---- kt 10..12 from LDS ----
        #pragma unroll
        for (int ktl = 0; ktl < 3; ++ktl) {
            const int kt = 10 + ktl;
            short8 bfr = *(const short8*)(hp + lm * 512 + ((((kt << 2) + lq) ^ lmx) << 3));
            #pragma unroll
            for (int j = 0; j < 4; ++j) {
                short8 wf = *(const short8*)(wlds + ((size_t)(ktl * 32 + wave * 4 + j) * 64 + lane) * 8);
                acc[j] = __builtin_amdgcn_mfma_f32_16x16x32_bf16(wf, bfr, acc[j], 0, 0, 0);
            }
        }
        // ---- kt 13..15 from stream regs ----
        {
            short8 bfr = *(const short8*)(hp + lm * 512 + ((((13 << 2) + lq) ^ lmx) << 3));
            #pragma unroll
            for (int j = 0; j < 4; ++j)
                acc[j] = __builtin_amdgcn_mfma_f32_16x16x32_bf16(sA[j], bfr, acc[j], 0, 0, 0);
        }
        {
            short8 bfr = *(const short8*)(hp + lm * 512 + ((((14 << 2) + lq) ^ lmx) << 3));
            #pragma unroll
            for (int j = 0; j < 4; ++j)
                acc[j] = __builtin_amdgcn_mfma_f32_16x16x32_bf16(sB[j], bfr, acc[j], 0, 0, 0);
        }
        {
            short8 bfr = *(const short8*)(hp + lm * 512 + ((((15 << 2) + lq) ^ lmx) << 3));
            #pragma unroll
            for (int j = 0; j < 4; ++j)
                acc[j] = __builtin_amdgcn_mfma_f32_16x16x32_bf16(sC[j], bfr, acc[j], 0, 0, 0);
        }

        // ---- epilogue: j = (wave*4+j)*16 + lq*4 + r, batch = bb ----
        #pragma unroll
        for (int j = 0; j < 4; ++j) {
            const int jb = (wave * 4 + j) * 16 + lq * 4;
            float q0 = tanh_fast(acc[j][0] + bf2f(xv[j].x));
            float q1 = tanh_fast(acc[j][1] + bf2f(xv[j].y));
            float q2 = tanh_fast(acc[j][2] + bf2f(xv[j].z));
            float q3 = tanh_fast(acc[j][3] + bf2f(xv[j].w));
            ushort4 pk;
            pk.x = f2bf(q0); pk.y = f2bf(q1); pk.z = f2bf(q2); pk.w = f2bf(q3);
            // swizzled LDS write: granule (jb>>3) ^ (lm&7), half-granule jb&7
            *(ushort4*)(hw + lm * 512 + (((jb >> 3) ^ lmx) << 3) + (jb & 7)) = pk;
            if (mode == 0) {
                *(ushort4*)(hs_out + xrow + jb) = pk;
            } else if (t == 511) {
                float4 o; o.x = q0; o.y = q1; o.z = q2; o.w = q3;
                *(float4*)(h_last + (size_t)bb * 512 + jb) = o;
            }
        }
        __syncthreads();
    }
}

// ---------------------------------------------------------------------------
// head: logits[b][c] = h_last[b][:]·W_out[c][:] + b_out[c]; log_softmax rows.
// ---------------------------------------------------------------------------
__global__ __launch_bounds__(256, 2) void head_kernel(
    const float* __restrict__ hl, const float* __restrict__ Wout,
    const float* __restrict__ bout, float* __restrict__ out)
{
    __shared__ float hrow[512];
    __shared__ float lg[1000];
    __shared__ float red[8];
    const int b = blockIdx.x, tid = threadIdx.x;

    hrow[tid]       = hl[(size_t)b * 512 + tid];
    hrow[tid + 256] = hl[(size_t)b * 512 + 256 + tid];
    __syncthreads();

    float lmax = -1e30f;
    for (int c = tid; c < 1000; c += 256) {
        const float4* w4 = (const float4*)(Wout + (size_t)c * 512);
        float a0 = 0.f, a1 = 0.f, a2 = 0.f, a3 = 0.f;
        #pragma unroll 4
        for (int k = 0; k < 128; ++k) {
            float4 w = w4[k];
            a0 += hrow[4 * k + 0] * w.x;
            a1 += hrow[4 * k + 1] * w.y;
            a2 += hrow[4 * k + 2] * w.z;
            a3 += hrow[4 * k + 3] * w.w;
        }
        float acc = bout[c] + (a0 + a1) + (a2 + a3);
        lg[c] = acc;
        lmax = fmaxf(lmax, acc);
    }
    #pragma unroll
    for (int off = 32; off; off >>= 1) lmax = fmaxf(lmax, __shfl_down(lmax, off, 64));
    if ((tid & 63) == 0) red[tid >> 6] = lmax;
    __syncthreads();
    if (tid == 0) red[4] = fmaxf(fmaxf(red[0], red[1]), fmaxf(red[2], red[3]));
    __syncthreads();
    const float M = red[4];

    float lsum = 0.f;
    for (int c = tid; c < 1000; c += 256) lsum += __expf(lg[c] - M);
    #pragma unroll
    for (int off = 32; off; off >>= 1) lsum += __shfl_down(lsum, off, 64);
    __syncthreads();
    if ((tid & 63) == 0) red[tid >> 6] = lsum;
    __syncthreads();
    if (tid == 0) red[5] = M + __logf(red[0] + red[1] + red[2] + red[3]);
    __syncthreads();
    const float lse = red[5];

    for (int c = tid; c < 1000; c += 256)
        out[(size_t)b * 1000 + c] = lg[c] - lse;
}

// ---------------------------------------------------------------------------
extern "C" void kernel_launch(void* const* d_in, const int* in_sizes, int n_in,
                              void* d_out, int out_size, void* d_ws, size_t ws_size,
                              hipStream_t stream)
{
    const float* x    = (const float*)d_in[0];
    const float* Wih0 = (const float*)d_in[1];
    const float* Whh0 = (const float*)d_in[2];
    const float* bih0 = (const float*)d_in[3];
    const float* bhh0 = (const float*)d_in[4];
    const float* Wih1 = (const float*)d_in[5];
    const float* Whh1 = (const float*)d_in[6];
    const float* bih1 = (const float*)d_in[7];
    const float* bhh1 = (const float*)d_in[8];
    const float* Wout = (const float*)d_in[9];
    const float* bout = (const float*)d_in[10];
    float* out = (float*)d_out;

    char* ws = (char*)d_ws;
    unsigned short* bufA = (unsigned short*)ws;                             // 64 MB
    unsigned short* bufB = (unsigned short*)(ws + (size_t)64 * 1024 * 1024);
    unsigned short* Wpk0 = bufB;                                            // 512 KB (dead after rec0)
    unsigned short* Wpk1 = bufA;                                            // 512 KB (bufA head, dead after proj1)
    float*         hlast = (float*)(ws + (size_t)1 * 1024 * 1024);          // 256 KB @ bufA+1MB

    const dim3 pgrid(8, 512);

    prepack_kernel<<<128, 256, 0, stream>>>(Whh0, Wpk0);
    proj_kernel<128, 0><<<pgrid, 256, 0, stream>>>((const void*)x, Wih0, bih0, bhh0, bufA);
    rec3_kernel<<<8, 512, 0, stream>>>(Wpk0, bufA, bufA, hlast, 0);

    proj_kernel<512, 1><<<pgrid, 256, 0, stream>>>((const void*)bufA, Wih1, bih1, bhh1, bufB);
    prepack_kernel<<<128, 256, 0, stream>>>(Whh1, Wpk1);
    rec3_kernel<<<8, 512, 0, stream>>>(Wpk1, bufB, bufB, hlast, 1);

    head_kernel<<<128, 256, 0, stream>>>(hlast, Wout, bout, out);
}

// Round 4
// 3350.847 us; speedup vs baseline: 2.1042x; 1.1183x over previous
//
#include <hip/hip_runtime.h>

// ============================================================================
// 2-layer tanh RNN (B=128,S=512,IN=128,H=512) + linear head (C=1000) + logsoftmax
//
// Round-4: batch-partitioned recurrence (8 WGs, zero cross-WG sync).
//   - 512 thr/WG (8 waves = 2/SIMD). Wave owns 4 j-tiles (64 j rows).
//   - W_hh 100% CU-resident: kt 0..11 in VGPRs (192/thread, PINNED with
//     asm volatile so the compiler cannot sink the loads into the loop —
//     round-3 failure mode, VGPR_Count=128 proved sinking), kt 12..15 in
//     LDS (128 KB, loaded once). ZERO per-step W traffic from L2.
//   - h state: LDS [2][16][512] bf16 double buffer, 16B-granule XOR swizzle
//     with lmx = (lm&7)^((lm>>1)&4) so lanes lm/lm+8 hit different banks.
//   - 1 __syncthreads per step.
//   - LDS total = 32768 + 131072 = 163840 B (exactly the 160 KiB max).
//
// ws layout: bufA = ws (64 MB): xp0/hs0 in place; Wpk1 at head later;
//            hlast @ ws+1MB; bufB = ws+64MB: Wpk0 at head, later xp1.
// ============================================================================

using short8  = __attribute__((ext_vector_type(8))) short;
using floatx4 = __attribute__((ext_vector_type(4))) float;

#define DEV static __device__ __forceinline__
#define PIN(x) asm volatile("" : "+v"(x))

DEV unsigned short f2bf(float f) {
    union { float f; unsigned u; } v; v.f = f;
    unsigned r = (v.u + 0x7fffu + ((v.u >> 16) & 1u)) >> 16;
    return (unsigned short)r;
}
DEV float bf2f(unsigned short h) {
    union { unsigned u; float f; } v; v.u = ((unsigned)h) << 16;
    return v.f;
}
DEV float tanh_fast(float x) {
    // tanh(x) = 1 - 2/(e^{2x}+1); saturates correctly at +/-inf
    float e = __expf(2.0f * x);
    return 1.0f - 2.0f * __builtin_amdgcn_rcpf(e + 1.0f);
}

// ---------------------------------------------------------------------------
// prepack: W_hh fp32 [512][512] -> bf16 A-frag order.
// frag = jtg*16 + kt; lane holds j = jtg*16+(lane&15), k = kt*32+(lane>>4)*8+e.
// ---------------------------------------------------------------------------
__global__ void prepack_kernel(const float* __restrict__ W,
                               unsigned short* __restrict__ Wpk)
{
    const int gid  = blockIdx.x * 256 + threadIdx.x;   // 0..32767
    const int lane = gid & 63;
    const int frag = gid >> 6;                         // 0..511
    const int kt   = frag & 15;
    const int jtg  = frag >> 4;
    const int j    = jtg * 16 + (lane & 15);
    const int k    = kt * 32 + (lane >> 4) * 8;
    const float* src = W + (size_t)j * 512 + k;
    float4 a = *(const float4*)(src);
    float4 b = *(const float4*)(src + 4);
    short8 p;
    p[0]=(short)f2bf(a.x); p[1]=(short)f2bf(a.y);
    p[2]=(short)f2bf(a.z); p[3]=(short)f2bf(a.w);
    p[4]=(short)f2bf(b.x); p[5]=(short)f2bf(b.y);
    p[6]=(short)f2bf(b.z); p[7]=(short)f2bf(b.w);
    *(short8*)(Wpk + (size_t)gid * 8) = p;
}

// ---------------------------------------------------------------------------
// proj: out[m=t*128+b][n] = bf16( A[m][:]·W[n][:] + b1[n]+b2[n] )  (unchanged)
// ---------------------------------------------------------------------------
template <int K, int MODE>
__global__ __launch_bounds__(256, 2) void proj_kernel(
    const void* __restrict__ Aptr, const float* __restrict__ W,
    const float* __restrict__ b1, const float* __restrict__ b2,
    unsigned short* __restrict__ out)
{
    constexpr int LDA = 40;
    __shared__ unsigned short As[128 * LDA];
    __shared__ unsigned short Ws[64 * LDA];

    const int tid  = threadIdx.x;
    const int lane = tid & 63, wave = tid >> 6;
    const int lm   = lane & 15, lq = lane >> 4;
    const int nbase = blockIdx.x * 64;
    const int mtile = blockIdx.y;
    const int mbase = mtile * 128;

    floatx4 acc[2][4] = {};

    const int ar = tid >> 1, ak = (tid & 1) * 16;
    const int wr = tid >> 2, wk = (tid & 3) * 8;

    for (int k0 = 0; k0 < K; k0 += 32) {
        if (MODE == 0) {
            const float* x   = (const float*)Aptr;
            const float* src = x + ((size_t)ar * 512 + mtile) * 128 + (k0 + ak);
            float4 f0 = *(const float4*)(src + 0);
            float4 f1 = *(const float4*)(src + 4);
            float4 f2 = *(const float4*)(src + 8);
            float4 f3 = *(const float4*)(src + 12);
            unsigned short* d = As + ar * LDA + ak;
            d[0]=f2bf(f0.x); d[1]=f2bf(f0.y); d[2]=f2bf(f0.z); d[3]=f2bf(f0.w);
            d[4]=f2bf(f1.x); d[5]=f2bf(f1.y); d[6]=f2bf(f1.z); d[7]=f2bf(f1.w);
            d[8]=f2bf(f2.x); d[9]=f2bf(f2.y); d[10]=f2bf(f2.z); d[11]=f2bf(f2.w);
            d[12]=f2bf(f3.x); d[13]=f2bf(f3.y); d[14]=f2bf(f3.z); d[15]=f2bf(f3.w);
        } else {
            const unsigned short* h =
                (const unsigned short*)Aptr + (size_t)(mbase + ar) * K + k0 + ak;
            short8 v0 = *(const short8*)(h);
            short8 v1 = *(const short8*)(h + 8);
            *(short8*)(As + ar * LDA + ak)     = v0;
            *(short8*)(As + ar * LDA + ak + 8) = v1;
        }
        {
            const float* src = W + (size_t)(nbase + wr) * K + k0 + wk;
            float4 f0 = *(const float4*)(src);
            float4 f1 = *(const float4*)(src + 4);
            unsigned short* d = Ws + wr * LDA + wk;
            d[0]=f2bf(f0.x); d[1]=f2bf(f0.y); d[2]=f2bf(f0.z); d[3]=f2bf(f0.w);
            d[4]=f2bf(f1.x); d[5]=f2bf(f1.y); d[6]=f2bf(f1.z); d[7]=f2bf(f1.w);
        }
        __syncthreads();

        short8 af0 = *(const short8*)(As + (wave * 32 +  0 + lm) * LDA + lq * 8);
        short8 af1 = *(const short8*)(As + (wave * 32 + 16 + lm) * LDA + lq * 8);
        #pragma unroll
        for (int nt = 0; nt < 4; ++nt) {
            short8 bf = *(const short8*)(Ws + (nt * 16 + lm) * LDA + lq * 8);
            acc[0][nt] = __builtin_amdgcn_mfma_f32_16x16x32_bf16(af0, bf, acc[0][nt], 0, 0, 0);
            acc[1][nt] = __builtin_amdgcn_mfma_f32_16x16x32_bf16(af1, bf, acc[1][nt], 0, 0, 0);
        }
        __syncthreads();
    }

    #pragma unroll
    for (int nt = 0; nt < 4; ++nt) {
        const int n = nbase + nt * 16 + lm;
        const float bias = b1[n] + b2[n];
        #pragma unroll
        for (int mt = 0; mt < 2; ++mt) {
            const int mrow = mbase + wave * 32 + mt * 16 + lq * 4;
            #pragma unroll
            for (int r = 0; r < 4; ++r)
                out[(size_t)(mrow + r) * 512 + n] = f2bf(acc[mt][nt][r] + bias);
        }
    }
}

// ---------------------------------------------------------------------------
// rec4: 8 WGs x 512 thr. WG bg owns batches [bg*16,+16), full H=512.
// Wave owns 4 j-tiles. W: kt 0..11 in pinned VGPRs, kt 12..15 in LDS.
// ---------------------------------------------------------------------------
__global__ __launch_bounds__(512, 2) void rec4_kernel(
    const unsigned short* __restrict__ Wpk,  // [512 frag][64 lane][8] bf16
    const unsigned short* xp,                // [S][B][H] bf16 (aliases hs_out)
    unsigned short* hs_out,                  // [S][B][H] bf16
    float* __restrict__ h_last,              // [B][H] fp32
    int mode)
{
    __shared__ unsigned short h2[2][16 * 512];        // 32 KB
    __shared__ unsigned short wlds[4 * 32 * 64 * 8];  // 128 KB  (total 160 KiB)

    const int tid  = threadIdx.x;
    const int lane = tid & 63;
    const int wave = tid >> 6;                 // 0..7
    const int lm   = lane & 15, lq = lane >> 4;
    const int bg   = blockIdx.x;
    const int bb   = bg * 16 + lm;             // this lane's batch column
    const int lmx  = (lm & 7) ^ ((lm >> 1) & 4);   // swizzle: lm vs lm+8 differ

    // ---- resident W frags: kt 0..11 for this wave's 4 j-tiles (192 VGPR) ----
    short8 wreg[4][12];
    #pragma unroll
    for (int j = 0; j < 4; ++j) {
        const int jtg = wave * 4 + j;
        #pragma unroll
        for (int kt = 0; kt < 12; ++kt)
            wreg[j][kt] = *(const short8*)(Wpk + ((size_t)(jtg * 16 + kt) * 64 + lane) * 8);
    }
    // Pin: the asm is volatile -> loads above cannot sink into the loop and
    // the values cannot be rematerialized. This is the round-3 fix.
    #pragma unroll
    for (int j = 0; j < 4; ++j)
        #pragma unroll
        for (int kt = 0; kt < 12; ++kt)
            PIN(wreg[j][kt]);

    // ---- load W kt 12..15 into LDS (layout [ktl][jtg][lane][8]) ----
    for (int i = tid; i < 4 * 32 * 64; i += 512) {
        const int l_  = i & 63;
        const int jg_ = (i >> 6) & 31;
        const int kl_ = i >> 11;              // 0..3
        *(short8*)(wlds + (size_t)i * 8) =
            *(const short8*)(Wpk + ((size_t)(jg_ * 16 + 12 + kl_) * 64 + l_) * 8);
    }

    // ---- zero h buffers ----
    for (int i = tid; i < 2 * 16 * 512; i += 512)
        ((unsigned short*)h2)[i] = 0;
    __syncthreads();

    for (int t = 0; t < 512; ++t) {
        const int p = t & 1;
        const unsigned short* hp = &h2[p][0];       // read h_{t-1}
        unsigned short*       hw = &h2[p ^ 1][0];   // write h_t

        // ---- xp operands for epilogue (issue early, consumed late) ----
        const size_t xrow = ((size_t)t * 128 + bb) * 512;
        ushort4 xv[4];
        #pragma unroll
        for (int j = 0; j < 4; ++j)
            xv[j] = *(const ushort4*)(xp + xrow + (wave * 4 + j) * 16 + lq * 4);

        floatx4 acc[4] = {};

        // ---- kt 0..11 from pinned registers ----
        #pragma unroll
        for (int kt = 0; kt < 12; ++kt) {
            short8 bfr = *(const short8*)(hp + lm * 512 + ((((kt << 2) + lq) ^ lmx) << 3));
            #pragma unroll
            for (int j = 0; j < 4; ++j)
                acc[j] = __builtin_amdgcn_mfma_f32_16x16x32_bf16(wreg[j][kt], bfr, acc[j], 0, 0, 0);
        }
        // ---- kt 12..15 from LDS ----
        #pragma unroll
        for (int ktl = 0; ktl < 4; ++ktl) {
            const int kt = 12 + ktl;
            short8 bfr = *(const short8*)(hp + lm * 512 + ((((kt << 2) + lq) ^ lmx) << 3));
            #pragma unroll
            for (int j = 0; j < 4; ++j) {
                short8 wf = *(const short8*)(wlds + ((size_t)(ktl * 32 + wave * 4 + j) * 64 + lane) * 8);
                acc[j] = __builtin_amdgcn_mfma_f32_16x16x32_bf16(wf, bfr, acc[j], 0, 0, 0);
            }
        }

        // ---- epilogue: j = (wave*4+j)*16 + lq*4 + r, batch = bb ----
        #pragma unroll
        for (int j = 0; j < 4; ++j) {
            const int jb = (wave * 4 + j) * 16 + lq * 4;
            float q0 = tanh_fast(acc[j][0] + bf2f(xv[j].x));
            float q1 = tanh_fast(acc[j][1] + bf2f(xv[j].y));
            float q2 = tanh_fast(acc[j][2] + bf2f(xv[j].z));
            float q3 = tanh_fast(acc[j][3] + bf2f(xv[j].w));
            ushort4 pk;
            pk.x = f2bf(q0); pk.y = f2bf(q1); pk.z = f2bf(q2); pk.w = f2bf(q3);
            // swizzled LDS write: logical granule (jb>>3) stored at ^lmx
            *(ushort4*)(hw + lm * 512 + (((jb >> 3) ^ lmx) << 3) + (jb & 7)) = pk;
            if (mode == 0) {
                *(ushort4*)(hs_out + xrow + jb) = pk;
            } else if (t == 511) {
                float4 o; o.x = q0; o.y = q1; o.z = q2; o.w = q3;
                *(float4*)(h_last + (size_t)bb * 512 + jb) = o;
            }
        }
        __syncthreads();
    }
}

// ---------------------------------------------------------------------------
// head: logits[b][c] = h_last[b][:]·W_out[c][:] + b_out[c]; log_softmax rows.
// ---------------------------------------------------------------------------
__global__ __launch_bounds__(256, 2) void head_kernel(
    const float* __restrict__ hl, const float* __restrict__ Wout,
    const float* __restrict__ bout, float* __restrict__ out)
{
    __shared__ float hrow[512];
    __shared__ float lg[1000];
    __shared__ float red[8];
    const int b = blockIdx.x, tid = threadIdx.x;

    hrow[tid]       = hl[(size_t)b * 512 + tid];
    hrow[tid + 256] = hl[(size_t)b * 512 + 256 + tid];
    __syncthreads();

    float lmax = -1e30f;
    for (int c = tid; c < 1000; c += 256) {
        const float4* w4 = (const float4*)(Wout + (size_t)c * 512);
        float a0 = 0.f, a1 = 0.f, a2 = 0.f, a3 = 0.f;
        #pragma unroll 4
        for (int k = 0; k < 128; ++k) {
            float4 w = w4[k];
            a0 += hrow[4 * k + 0] * w.x;
            a1 += hrow[4 * k + 1] * w.y;
            a2 += hrow[4 * k + 2] * w.z;
            a3 += hrow[4 * k + 3] * w.w;
        }
        float acc = bout[c] + (a0 + a1) + (a2 + a3);
        lg[c] = acc;
        lmax = fmaxf(lmax, acc);
    }
    #pragma unroll
    for (int off = 32; off; off >>= 1) lmax = fmaxf(lmax, __shfl_down(lmax, off, 64));
    if ((tid & 63) == 0) red[tid >> 6] = lmax;
    __syncthreads();
    if (tid == 0) red[4] = fmaxf(fmaxf(red[0], red[1]), fmaxf(red[2], red[3]));
    __syncthreads();
    const float M = red[4];

    float lsum = 0.f;
    for (int c = tid; c < 1000; c += 256) lsum += __expf(lg[c] - M);
    #pragma unroll
    for (int off = 32; off; off >>= 1) lsum += __shfl_down(lsum, off, 64);
    __syncthreads();
    if ((tid & 63) == 0) red[tid >> 6] = lsum;
    __syncthreads();
    if (tid == 0) red[5] = M + __logf(red[0] + red[1] + red[2] + red[3]);
    __syncthreads();
    const float lse = red[5];

    for (int c = tid; c < 1000; c += 256)
        out[(size_t)b * 1000 + c] = lg[c] - lse;
}

// ---------------------------------------------------------------------------
extern "C" void kernel_launch(void* const* d_in, const int* in_sizes, int n_in,
                              void* d_out, int out_size, void* d_ws, size_t ws_size,
                              hipStream_t stream)
{
    const float* x    = (const float*)d_in[0];
    const float* Wih0 = (const float*)d_in[1];
    const float* Whh0 = (const float*)d_in[2];
    const float* bih0 = (const float*)d_in[3];
    const float* bhh0 = (const float*)d_in[4];
    const float* Wih1 = (const float*)d_in[5];
    const float* Whh1 = (const float*)d_in[6];
    const float* bih1 = (const float*)d_in[7];
    const float* bhh1 = (const float*)d_in[8];
    const float* Wout = (const float*)d_in[9];
    const float* bout = (const float*)d_in[10];
    float* out = (float*)d_out;

    char* ws = (char*)d_ws;
    unsigned short* bufA = (unsigned short*)ws;                             // 64 MB
    unsigned short* bufB = (unsigned short*)(ws + (size_t)64 * 1024 * 1024);
    unsigned short* Wpk0 = bufB;                                            // 512 KB (dead after rec0)
    unsigned short* Wpk1 = bufA;                                            // 512 KB (bufA head, dead after proj1)
    float*         hlast = (float*)(ws + (size_t)1 * 1024 * 1024);          // 256 KB @ bufA+1MB

    const dim3 pgrid(8, 512);

    prepack_kernel<<<128, 256, 0, stream>>>(Whh0, Wpk0);
    proj_kernel<128, 0><<<pgrid, 256, 0, stream>>>((const void*)x, Wih0, bih0, bhh0, bufA);
    rec4_kernel<<<8, 512, 0, stream>>>(Wpk0, bufA, bufA, hlast, 0);

    proj_kernel<512, 1><<<pgrid, 256, 0, stream>>>((const void*)bufA, Wih1, bih1, bhh1, bufB);
    prepack_kernel<<<128, 256, 0, stream>>>(Whh1, Wpk1);
    rec4_kernel<<<8, 512, 0, stream>>>(Wpk1, bufB, bufB, hlast, 1);

    head_kernel<<<128, 256, 0, stream>>>(hlast, Wout, bout, out);
}